// Round 12
// baseline (248.277 us; speedup 1.0000x reference)
//
#include <hip/hip_runtime.h>
#include <hip/hip_bf16.h>

// Problem dims (fixed by reference): E=8, D=2048, B=4096, 3 layers.
#define MDIM 4096
#define NDIM 2048
#define KDIM 2048
#define KTILES 32          // K / 64
#define PER_LAYER 4194304  // 2048*2048

typedef __attribute__((ext_vector_type(8))) short bf16x8;   // 8 bf16 (4 VGPRs)
typedef __attribute__((ext_vector_type(4))) float f32x4;    // MFMA accumulator

__device__ __forceinline__ unsigned short f2bf(float f) {
    unsigned u = __builtin_bit_cast(unsigned, f);
    u += 0x7FFFu + ((u >> 16) & 1u);        // round-to-nearest-even
    return (unsigned short)(u >> 16);
}

// Fragment-major B layout: element (n,k) of the blended N x K weight lives at
//   dst = ((n>>4)*64 + (k>>5))*512 + ((n&15) + (((k>>3)&3)<<4))*8 + (k&7)
// so one mfma_16x16x32 B-fragment (ntile, kfrag) is 1KB contiguous, with
// lane l owning bytes [l*16, l*16+16) -- a single coalesced dwordx4 per lane.
__device__ __forceinline__ unsigned bfrag_off(unsigned n, unsigned k) {
    return ((n >> 4) * 64u + (k >> 5)) * 512u
         + (((n & 15u) + (((k >> 3) & 3u) << 4)) << 3) + (k & 7u);
}

// ---------------------------------------------------------------------------
// Kernel 1: blend layer-0 experts (frag-major bf16 out) + convert x to bf16.
// Reads 134MB W0 + 32MB x -> ~26us HBM-bound.
// ---------------------------------------------------------------------------
__global__ __launch_bounds__(256) void blend0_kernel(
    const float* __restrict__ W, const float* __restrict__ cb,
    const float* __restrict__ x,
    unsigned short* __restrict__ wb, unsigned short* __restrict__ xb)
{
    float c[8];
#pragma unroll
    for (int e = 0; e < 8; ++e) c[e] = cb[e];
    const unsigned wtotal4 = PER_LAYER >> 2;        // 1,048,576 float4 units
    const unsigned xtotal4 = 2097152u;              // 8M / 4
    const unsigned total = wtotal4 + xtotal4;
    unsigned stride = gridDim.x * blockDim.x;
    for (unsigned i = blockIdx.x * blockDim.x + threadIdx.x; i < total; i += stride) {
        if (i < wtotal4) {
            unsigned off = i << 2;                   // f32 idx = n*2048 + k
            const float* base = W + off;
            float4 s = make_float4(0.f, 0.f, 0.f, 0.f);
#pragma unroll
            for (int e = 0; e < 8; ++e) {
                float4 v = *(const float4*)(base + (size_t)e * PER_LAYER);
                s.x += c[e] * v.x; s.y += c[e] * v.y;
                s.z += c[e] * v.z; s.w += c[e] * v.w;
            }
            ushort4 o;
            o.x = f2bf(s.x); o.y = f2bf(s.y); o.z = f2bf(s.z); o.w = f2bf(s.w);
            *(ushort4*)(wb + bfrag_off(off >> 11, off & 2047u)) = o;
        } else {
            unsigned j = (i - wtotal4) << 2;
            float4 v = *(const float4*)(x + j);
            ushort4 o;
            o.x = f2bf(v.x); o.y = f2bf(v.y); o.z = f2bf(v.z); o.w = f2bf(v.w);
            *(ushort4*)(xb + j) = o;
        }
    }
}

// ---------------------------------------------------------------------------
// Kernel 2: 256x128 bf16 GEMM; A via LDS (3-buf 96KB, 2-tile-deep gload_lds,
// both-sides XOR swizzle); B via GLOBAL->REG from frag-major layout (1KB
// coalesced per fragment, 1-tile-deep named-reg double buffer bE/bO);
// fused next-layer blend (frag-major out).
//   C[M,N] = A[M,K] * Bfrag[N,K]^T + bias, optional ELU.
// grid = 256 (all CUs), 512 threads = 8 waves (4M x 2N), wave 64x64.
// LDS/K-tile: A 32KB write + 64KB read (was 176KB total) -> ~770 cyc reads.
// FIFO ledger per iter t: [blend9 (t%4==0)] -> B(t+1)x8 -> Astage(t+2)x4;
// end-of-iter VMC(4) drains A(t+1)+B(t+1)(+blend), leaves A(t+2) in flight.
// WAR: A-stage target buf (t+2)%3 last read iter t-1, barrier-separated.
// ---------------------------------------------------------------------------
#define BARR() do { asm volatile("" ::: "memory"); __builtin_amdgcn_s_barrier(); asm volatile("" ::: "memory"); } while (0)
#define SP(N) __builtin_amdgcn_s_setprio(N)
#define VMC_IMPL(N) asm volatile("s_waitcnt vmcnt(" #N ")" ::: "memory")
#define VMC(N) VMC_IMPL(N)

template<int ACT, typename OutT, int BLEND>
__global__ __launch_bounds__(512, 2) void gemm_bfrag(
    const unsigned short* __restrict__ A,   // M x K bf16 bits (row-major)
    const unsigned short* __restrict__ Bw,  // frag-major blended weights
    const float* __restrict__ bias,         // N
    OutT* __restrict__ C,                   // M x N
    const float* __restrict__ Wnext,        // 8 x 2048 x 2048 f32 (or null)
    const float* __restrict__ cb,           // (8,) blend coeffs (or null)
    unsigned short* __restrict__ wbNext)    // frag-major bf16 out (or null)
{
    __shared__ __align__(16) unsigned short lds[49152];   // 96 KB (A only)
    char* ldsc = (char*)lds;

    const int tid = threadIdx.x;
    const int wid = tid >> 6;
    const int lane = tid & 63;
    const int wr = wid >> 1;      // 0..3 (M)
    const int wc = wid & 1;       // 0..1 (N)

    // blend coeffs: load + fence BEFORE any counted vmem ops.
    float cw[8];
    if (BLEND) {
#pragma unroll
        for (int e = 0; e < 8; ++e) cw[e] = cb[e];
        VMC(0);
    }

    // bijective XCD-chunked swizzle: XCD k gets wg in [k*32,(k+1)*32)
    // = 2 N-panels x 16 M-tiles -> B frag panels (1MB) L2-resident per XCD.
    const int wg = (blockIdx.x & 7) * 32 + (blockIdx.x >> 3);
    const size_t blockM = (size_t)(wg & 15) * 256;
    const size_t blockN = (size_t)(wg >> 4) * 128;

    // A ds_read addressing: swizzled 16B slot within a 128B row.
    const int sw = (lane & 7) << 4;          // (row&7)<<4; row&7 == lane&7
    const int ck = (lane >> 4) << 4;         // k-slot byte base
    const int rAb = wr * 64 + (lane & 15);   // + m*16

    // A staging: thread t writes LDS bytes [tid*16, tid*16+16) of an 8KB
    // 64-row stage; source column pre-XORed (both-sides swizzle).
    const int srow = tid >> 3;                       // 0..63
    const int scol = ((tid & 7) ^ (srow & 7)) << 3;  // element offset
    const unsigned short* aStage = A + (blockM + srow) * KDIM + scol;

    // B frag base: wave wc covers ntiles (blockN>>4)+wc*4 .. +3; lane-contig.
    const unsigned short* bBase =
        Bw + ((size_t)((blockN >> 4) + wc * 4) * 64) * 512 + lane * 8;

#define STAGE_A(BUF, S, KT) do { \
    const unsigned short* g_ = aStage + (size_t)(S) * 64 * KDIM + (size_t)(KT) * 64; \
    __builtin_amdgcn_global_load_lds((const __attribute__((address_space(1))) void*)g_, \
        (__attribute__((address_space(3))) void*)(ldsc + (BUF) * 32768 + (S) * 8192 + tid * 16), \
        16, 0, 0); \
} while (0)

#define STAGE_A4(BUF, KT) do { \
    STAGE_A(BUF, 0, KT); STAGE_A(BUF, 1, KT); STAGE_A(BUF, 2, KT); STAGE_A(BUF, 3, KT); \
} while (0)

#define RD_A(BUF, M, KK) \
    (*(const bf16x8*)(ldsc + (BUF) * 32768 + (rAb + (M) * 16) * 128 + (((KK) * 64 + ck) ^ sw)))

// load tile T's 8 B-fragments into DST (coalesced 1KB each, L2-hot)
#define LOAD_B(DST, T) do { _Pragma("unroll") for (int n_ = 0; n_ < 4; ++n_) { \
    DST[n_][0] = *(const bf16x8*)(bBase + (size_t)n_ * 32768 + (size_t)(T) * 1024); \
    DST[n_][1] = *(const bf16x8*)(bBase + (size_t)n_ * 32768 + (size_t)(T) * 1024 + 512); } } while (0)

    f32x4 acc[4][4];
#pragma unroll
    for (int m = 0; m < 4; ++m)
#pragma unroll
        for (int n = 0; n < 4; ++n) acc[m][n] = (f32x4){0.f, 0.f, 0.f, 0.f};

    bf16x8 bE[4][2], bO[4][2];

    // one blend chunk: thread blends float4 #(G*131072 + bid*512 + tid)
#define BLEND_STEP(G) do { \
    const unsigned idx_ = (unsigned)(G) * 131072u + (unsigned)blockIdx.x * 512u + (unsigned)tid; \
    const unsigned off_ = idx_ << 2; \
    const float* bs_ = Wnext + off_; \
    float4 s_ = make_float4(0.f, 0.f, 0.f, 0.f); \
    _Pragma("unroll") for (int e_ = 0; e_ < 8; ++e_) { \
        float4 v_ = *(const float4*)(bs_ + (size_t)e_ * PER_LAYER); \
        s_.x += cw[e_] * v_.x; s_.y += cw[e_] * v_.y; \
        s_.z += cw[e_] * v_.z; s_.w += cw[e_] * v_.w; } \
    ushort4 o_; \
    o_.x = f2bf(s_.x); o_.y = f2bf(s_.y); o_.z = f2bf(s_.z); o_.w = f2bf(s_.w); \
    *(ushort4*)(wbNext + bfrag_off(off_ >> 11, off_ & 2047u)) = o_; \
} while (0)

    // One K-tile: ds_read A, [blend], load B(t+1)->BNXT, stage A(t+2), MFMA
    // with BCUR, counted wait, barrier.
#define GEMM_ITER(T, BCUR, BNXT, WAITER) do { \
    int stb_ = cur + 2; if (stb_ >= 3) stb_ -= 3; \
    bf16x8 af[4][2]; \
    _Pragma("unroll") for (int m_ = 0; m_ < 4; ++m_) { \
        af[m_][0] = RD_A(cur, m_, 0); af[m_][1] = RD_A(cur, m_, 1); } \
    if (BLEND && ((T) & 3) == 0) BLEND_STEP((T) >> 2); \
    if ((T) + 1 < KTILES) LOAD_B(BNXT, (T) + 1); \
    if ((T) + 2 < KTILES) STAGE_A4(stb_, (T) + 2); \
    SP(1); \
    _Pragma("unroll") for (int kk_ = 0; kk_ < 2; ++kk_) \
    _Pragma("unroll") for (int m_ = 0; m_ < 4; ++m_) \
    _Pragma("unroll") for (int n_ = 0; n_ < 4; ++n_) \
        acc[m_][n_] = __builtin_amdgcn_mfma_f32_16x16x32_bf16( \
            af[m_][kk_], BCUR[n_][kk_], acc[m_][n_], 0, 0, 0); \
    SP(0); \
    WAITER; \
    BARR(); \
    cur = cur + 1; if (cur >= 3) cur = 0; \
} while (0)

    // ---- prologue: A tile0->buf0, B(0)->bE, A tile1->buf1 ----
    STAGE_A4(0, 0);               // 4 ops
    LOAD_B(bE, 0);                // 8 ops
    STAGE_A4(1, 1);               // 4 ops
    VMC(4);                       // drains A(0)+B(0); A(1) in flight
    BARR();

    int cur = 0;
#pragma unroll 1
    for (int t = 0; t < 30; t += 2) {
        GEMM_ITER(t,     bE, bO, VMC(4));
        GEMM_ITER(t + 1, bO, bE, VMC(4));
    }
    GEMM_ITER(30, bE, bO, VMC(0));   // loads B(31), stages nothing, drains all
    GEMM_ITER(31, bO, bE, VMC(0));   // final tile

    // ---- epilogue: C/D layout col=lane&15 (N), row=(lane>>4)*4+reg (M) ----
    const int crow = (lane >> 4) * 4;
    const int ccol = lane & 15;
#pragma unroll
    for (int m = 0; m < 4; ++m)
#pragma unroll
        for (int n = 0; n < 4; ++n) {
            const size_t col = blockN + wc * 64 + n * 16 + ccol;
            const float bv = bias[col];
#pragma unroll
            for (int r = 0; r < 4; ++r) {
                const size_t row = blockM + wr * 64 + m * 16 + crow + r;
                float v = acc[m][n][r] + bv;
                if (ACT) v = v > 0.f ? v : expm1f(v);
                if constexpr (sizeof(OutT) == 2) {
                    C[row * NDIM + col] = (OutT)f2bf(v);
                } else {
                    C[row * NDIM + col] = (OutT)v;
                }
            }
        }
#undef STAGE_A
#undef STAGE_A4
#undef RD_A
#undef LOAD_B
#undef GEMM_ITER
#undef BLEND_STEP
}

// ---------------------------------------------------------------------------
// Launch: blend0+convert, then 3 chained GEMMs; GEMM0 blends W1, GEMM1
// blends W2 (overlapped with compute), GEMM2 plain.
// Workspace (ushort units): wb[3*PER_LAYER] frag-major weights, xb, y0.
// ---------------------------------------------------------------------------
extern "C" void kernel_launch(void* const* d_in, const int* in_sizes, int n_in,
                              void* d_out, int out_size, void* d_ws, size_t ws_size,
                              hipStream_t stream) {
    const float* blendw = (const float*)d_in[0];   // (8,)
    const float* x      = (const float*)d_in[1];   // (4096, 2048)
    const float* W      = (const float*)d_in[2];   // (3, 8, 2048, 2048)
    const float* Bb     = (const float*)d_in[3];   // (3, 2048)
    float* out = (float*)d_out;                    // (4096, 2048) f32

    unsigned short* wb0 = (unsigned short*)d_ws;
    unsigned short* wb1 = wb0 + PER_LAYER;
    unsigned short* wb2 = wb1 + PER_LAYER;
    unsigned short* xb  = wb2 + PER_LAYER;
    unsigned short* y0  = xb + 8388608;
    unsigned short* y1  = xb;   // reuse: xb dead after GEMM0

    blend0_kernel<<<2048, 256, 0, stream>>>(W, blendw, x, wb0, xb);

    const int grid = (MDIM / 256) * (NDIM / 128);    // 256 blocks = all CUs
    gemm_bfrag<1, unsigned short, 1><<<grid, 512, 0, stream>>>(
        xb, wb0, Bb,        y0,  W + (size_t)8 * PER_LAYER,  blendw, wb1);
    gemm_bfrag<1, unsigned short, 1><<<grid, 512, 0, stream>>>(
        y0, wb1, Bb + 2048, y1,  W + (size_t)16 * PER_LAYER, blendw, wb2);
    gemm_bfrag<0, float, 0><<<grid, 512, 0, stream>>>(
        y1, wb2, Bb + 4096, out, nullptr, nullptr, nullptr);
}

// Round 13
// 228.478 us; speedup vs baseline: 1.0867x; 1.0867x over previous
//
#include <hip/hip_runtime.h>
#include <hip/hip_bf16.h>

// Problem dims (fixed by reference): E=8, D=2048, B=4096, 3 layers.
#define MDIM 4096
#define NDIM 2048
#define KDIM 2048
#define KTILES 32          // K / 64
#define PER_LAYER 4194304  // 2048*2048

typedef __attribute__((ext_vector_type(8))) short bf16x8;   // 8 bf16 (4 VGPRs)
typedef __attribute__((ext_vector_type(4))) float f32x4;    // MFMA accumulator

__device__ __forceinline__ unsigned short f2bf(float f) {
    unsigned u = __builtin_bit_cast(unsigned, f);
    u += 0x7FFFu + ((u >> 16) & 1u);        // round-to-nearest-even
    return (unsigned short)(u >> 16);
}

#define BARR() do { asm volatile("" ::: "memory"); __builtin_amdgcn_s_barrier(); asm volatile("" ::: "memory"); } while (0)
#define SP(N) __builtin_amdgcn_s_setprio(N)
#define LGKM0() asm volatile("s_waitcnt lgkmcnt(0)" ::: "memory")
#define VMC_IMPL(N) asm volatile("s_waitcnt vmcnt(" #N ")" ::: "memory")
#define VMC(N) VMC_IMPL(N)

// ---------------------------------------------------------------------------
// Kernel 1: blend layer-0 experts only (x-convert is fused into GEMM0;
// W1/W2 blends are fused into GEMM0/GEMM1). 134MB read -> ~22us HBM-bound.
// ---------------------------------------------------------------------------
__global__ __launch_bounds__(256) void blend0_kernel(
    const float* __restrict__ W, const float* __restrict__ cb,
    unsigned short* __restrict__ wb)
{
    float c[8];
#pragma unroll
    for (int e = 0; e < 8; ++e) c[e] = cb[e];
    const unsigned wtotal4 = PER_LAYER >> 2;        // 1,048,576 float4 units
    unsigned stride = gridDim.x * blockDim.x;
    for (unsigned i = blockIdx.x * blockDim.x + threadIdx.x; i < wtotal4; i += stride) {
        unsigned off = i << 2;
        const float* base = W + off;
        float4 s = make_float4(0.f, 0.f, 0.f, 0.f);
#pragma unroll
        for (int e = 0; e < 8; ++e) {
            float4 v = *(const float4*)(base + (size_t)e * PER_LAYER);
            s.x += c[e] * v.x; s.y += c[e] * v.y;
            s.z += c[e] * v.z; s.w += c[e] * v.w;
        }
        ushort4 o;
        o.x = f2bf(s.x); o.y = f2bf(s.y); o.z = f2bf(s.z); o.w = f2bf(s.w);
        *(ushort4*)(wb + off) = o;
    }
}

// ---------------------------------------------------------------------------
// Kernel 2a (GEMM0): A = x in FP32, converted to bf16 during reg-staging.
// 256x128 tile, 2-buf LDS 96KB (A 32K + B 16K per buf), 8 waves (4M x 2N,
// wave 64x64), 1-deep stage with full intra-iter latency cover; fused W1
// blend.  C = ELU(x @ wb0^T + bias) in bf16; wbNext = sum_e c_e W1_e.
// Per iter t: [blend(t%4==0): 9 vmem] -> issue 8 x-loads(t+1) + 2 B-gload(t+1)
// -> ds_read cur (16 b128) -> 32 MFMA -> VMC(2) (x-loads+blend drained)
// -> cvt+4x ds_write_b128 -> VMC(0) (B landed) -> lgkm0 -> barrier.
// WAR: write target buf cur^1 holds tile t-1, read finished before the
// end-of-(t-1) barrier. RAW: VMC(0)+lgkm0+barrier publish tile t+1.
// ---------------------------------------------------------------------------
template<int ACT, typename OutT>
__global__ __launch_bounds__(512, 2) void gemm_x32(
    const float* __restrict__ X,             // M x K f32 (A operand)
    const unsigned short* __restrict__ Bw,   // N x K bf16 bits (blended W0)
    const float* __restrict__ bias,          // N
    OutT* __restrict__ C,                    // M x N
    const float* __restrict__ Wnext,         // 8 x 2048 x 2048 f32
    const float* __restrict__ cb,            // (8,) blend coeffs
    unsigned short* __restrict__ wbNext)     // 2048 x 2048 bf16 out
{
    __shared__ __align__(16) unsigned short lds[49152];   // 96 KB (2 bufs)
    char* ldsc = (char*)lds;

    const int tid = threadIdx.x;
    const int wid = tid >> 6;
    const int lane = tid & 63;
    const int wr = wid >> 1;      // 0..3 (M)
    const int wc = wid & 1;       // 0..1 (N)

    float cw[8];
#pragma unroll
    for (int e = 0; e < 8; ++e) cw[e] = cb[e];
    VMC(0);                       // coeffs out of the vmcnt ledger

    const int wg = (blockIdx.x & 7) * 32 + (blockIdx.x >> 3);
    const size_t blockM = (size_t)(wg & 15) * 256;
    const size_t blockN = (size_t)(wg >> 4) * 128;

    const int sw = (lane & 7) << 4;
    const int ck = (lane >> 4) << 4;
    const int rAb = wr * 64 + (lane & 15);
    const int rBb = wc * 64 + (lane & 15);

    const int srow = tid >> 3;                       // 0..63
    const int scol = ((tid & 7) ^ (srow & 7)) << 3;  // element offset
    const float* xStage = X + (blockM + srow) * KDIM + scol;
    const unsigned short* bStage = Bw + (blockN + srow) * KDIM + scol;

#define STAGE_BS(BUF, S, KT) do { \
    const unsigned short* g_ = bStage + (size_t)(S) * 64 * KDIM + (size_t)(KT) * 64; \
    __builtin_amdgcn_global_load_lds((const __attribute__((address_space(1))) void*)g_, \
        (__attribute__((address_space(3))) void*)(ldsc + (BUF) * 49152 + 32768 + (S) * 8192 + tid * 16), \
        16, 0, 0); \
} while (0)

// issue 8 x-loads (2 float4 per slab) for tile KT into ra[]
#define XLOAD(RA, KT) do { _Pragma("unroll") for (int s_ = 0; s_ < 4; ++s_) { \
    const float* g_ = xStage + (size_t)s_ * 64 * KDIM + (size_t)(KT) * 64; \
    RA[2 * s_]     = *(const float4*)g_; \
    RA[2 * s_ + 1] = *(const float4*)(g_ + 4); } } while (0)

// cvt + write the staged tile into buf's A region (4x ds_write_b128)
#define XWRITE(RA, BUF) do { _Pragma("unroll") for (int s_ = 0; s_ < 4; ++s_) { \
    ushort4 lo_, hi_; \
    lo_.x = f2bf(RA[2 * s_].x); lo_.y = f2bf(RA[2 * s_].y); \
    lo_.z = f2bf(RA[2 * s_].z); lo_.w = f2bf(RA[2 * s_].w); \
    hi_.x = f2bf(RA[2 * s_ + 1].x); hi_.y = f2bf(RA[2 * s_ + 1].y); \
    hi_.z = f2bf(RA[2 * s_ + 1].z); hi_.w = f2bf(RA[2 * s_ + 1].w); \
    ushort4 pk_[2] = { lo_, hi_ }; \
    *(ushort4*)(ldsc + (BUF) * 49152 + s_ * 8192 + tid * 16) = pk_[0]; \
    *(ushort4*)(ldsc + (BUF) * 49152 + s_ * 8192 + tid * 16 + 8) = pk_[1]; } } while (0)

#define RD_A(BUF, M, KK) \
    (*(const bf16x8*)(ldsc + (BUF) * 49152 + (rAb + (M) * 16) * 128 + (((KK) * 64 + ck) ^ sw)))
#define RD_B(BUF, N, KK) \
    (*(const bf16x8*)(ldsc + (BUF) * 49152 + 32768 + (rBb + (N) * 16) * 128 + (((KK) * 64 + ck) ^ sw)))

#define BLEND_STEP(G) do { \
    const unsigned idx_ = (unsigned)(G) * 131072u + (unsigned)blockIdx.x * 512u + (unsigned)tid; \
    const unsigned off_ = idx_ << 2; \
    const float* bs_ = Wnext + off_; \
    float4 s_ = make_float4(0.f, 0.f, 0.f, 0.f); \
    _Pragma("unroll") for (int e_ = 0; e_ < 8; ++e_) { \
        float4 v_ = *(const float4*)(bs_ + (size_t)e_ * PER_LAYER); \
        s_.x += cw[e_] * v_.x; s_.y += cw[e_] * v_.y; \
        s_.z += cw[e_] * v_.z; s_.w += cw[e_] * v_.w; } \
    ushort4 o_; \
    o_.x = f2bf(s_.x); o_.y = f2bf(s_.y); o_.z = f2bf(s_.z); o_.w = f2bf(s_.w); \
    *(ushort4*)(wbNext + off_) = o_; \
} while (0)

    f32x4 acc[4][4];
#pragma unroll
    for (int m = 0; m < 4; ++m)
#pragma unroll
        for (int n = 0; n < 4; ++n) acc[m][n] = (f32x4){0.f, 0.f, 0.f, 0.f};

    // ---- prologue: tile0 -> buf0 (x via regs, B via gload_lds) ----
    {
        float4 ra[8];
        XLOAD(ra, 0);                 // 8 vmem
        STAGE_BS(0, 0, 0); STAGE_BS(0, 1, 0);   // 2 vmem
        VMC(2);                       // x(0) landed
        XWRITE(ra, 0);
        VMC(0);                       // B(0) landed
        LGKM0();
        BARR();
    }

#pragma unroll 1
    for (int t = 0; t < KTILES; ++t) {
        const int cur = t & 1, nxt = cur ^ 1;
        float4 ra[8];
        if ((t & 3) == 0) BLEND_STEP(t >> 2);            // 9 vmem
        if (t + 1 < KTILES) {
            XLOAD(ra, t + 1);                            // 8 vmem
            STAGE_BS(nxt, 0, t + 1); STAGE_BS(nxt, 1, t + 1);  // 2 vmem
        }
        bf16x8 af[4][2], bfr[4][2];
#pragma unroll
        for (int m = 0; m < 4; ++m) { af[m][0] = RD_A(cur, m, 0); af[m][1] = RD_A(cur, m, 1); }
#pragma unroll
        for (int n = 0; n < 4; ++n) { bfr[n][0] = RD_B(cur, n, 0); bfr[n][1] = RD_B(cur, n, 1); }
        SP(1);
#pragma unroll
        for (int kk = 0; kk < 2; ++kk)
#pragma unroll
            for (int m = 0; m < 4; ++m)
#pragma unroll
                for (int n = 0; n < 4; ++n)
                    acc[m][n] = __builtin_amdgcn_mfma_f32_16x16x32_bf16(
                        af[m][kk], bfr[n][kk], acc[m][n], 0, 0, 0);
        SP(0);
        if (t + 1 < KTILES) {
            VMC(2);                   // blend + x(t+1) drained; B(t+1) may fly
            XWRITE(ra, nxt);
            VMC(0);                   // B(t+1) landed
        } else {
            VMC(0);
        }
        LGKM0();
        BARR();
    }

    const int crow = (lane >> 4) * 4;
    const int ccol = lane & 15;
#pragma unroll
    for (int m = 0; m < 4; ++m)
#pragma unroll
        for (int n = 0; n < 4; ++n) {
            const size_t col = blockN + wc * 64 + n * 16 + ccol;
            const float bv = bias[col];
#pragma unroll
            for (int r = 0; r < 4; ++r) {
                const size_t row = blockM + wr * 64 + m * 16 + crow + r;
                float v = acc[m][n][r] + bv;
                if (ACT) v = v > 0.f ? v : expm1f(v);
                if constexpr (sizeof(OutT) == 2) {
                    C[row * NDIM + col] = (OutT)f2bf(v);
                } else {
                    C[row * NDIM + col] = (OutT)v;
                }
            }
        }
#undef STAGE_BS
#undef XLOAD
#undef XWRITE
#undef RD_A
#undef RD_B
#undef BLEND_STEP
}

// ---------------------------------------------------------------------------
// Kernel 2b: r7 GEMM verbatim (256x128, 3-buf LDS 144KB, 2-deep prefetch,
// counted vmcnt, fused optional blend). Used for GEMM1 / GEMM2.
// ---------------------------------------------------------------------------
template<int ACT, typename OutT, int BLEND>
__global__ __launch_bounds__(512, 2) void gemm_fused(
    const unsigned short* __restrict__ A,
    const unsigned short* __restrict__ Bw,
    const float* __restrict__ bias,
    OutT* __restrict__ C,
    const float* __restrict__ Wnext,
    const float* __restrict__ cb,
    unsigned short* __restrict__ wbNext)
{
    __shared__ __align__(16) unsigned short lds[73728];   // 144 KB
    char* ldsc = (char*)lds;

    const int tid = threadIdx.x;
    const int wid = tid >> 6;
    const int lane = tid & 63;
    const int wr = wid >> 1;
    const int wc = wid & 1;

    float cw[8];
    if (BLEND) {
#pragma unroll
        for (int e = 0; e < 8; ++e) cw[e] = cb[e];
        VMC(0);
    }

    const int wg = (blockIdx.x & 7) * 32 + (blockIdx.x >> 3);
    const size_t blockM = (size_t)(wg & 15) * 256;
    const size_t blockN = (size_t)(wg >> 4) * 128;

    const int sw = (lane & 7) << 4;
    const int ck = (lane >> 4) << 4;
    const int rAb = wr * 64 + (lane & 15);
    const int rBb = wc * 64 + (lane & 15);

    const int srow = tid >> 3;
    const int scol = ((tid & 7) ^ (srow & 7)) << 3;
    const unsigned short* aStage = A + (blockM + srow) * KDIM + scol;
    const unsigned short* bStage = Bw + (blockN + srow) * KDIM + scol;

#define STAGE_AS(BUF, S, KT) do { \
    const unsigned short* g_ = aStage + (size_t)(S) * 64 * KDIM + (size_t)(KT) * 64; \
    __builtin_amdgcn_global_load_lds((const __attribute__((address_space(1))) void*)g_, \
        (__attribute__((address_space(3))) void*)(ldsc + (BUF) * 49152 + (S) * 8192 + tid * 16), \
        16, 0, 0); \
} while (0)

#define STAGE_BS(BUF, S, KT) do { \
    const unsigned short* g_ = bStage + (size_t)(S) * 64 * KDIM + (size_t)(KT) * 64; \
    __builtin_amdgcn_global_load_lds((const __attribute__((address_space(1))) void*)g_, \
        (__attribute__((address_space(3))) void*)(ldsc + (BUF) * 49152 + 32768 + (S) * 8192 + tid * 16), \
        16, 0, 0); \
} while (0)

#define RD_A(BUF, M, KK) \
    (*(const bf16x8*)(ldsc + (BUF) * 49152 + ((rAb + (M) * 16)) * 128 + (((KK) * 64 + ck) ^ sw)))
#define RD_B(BUF, N, KK) \
    (*(const bf16x8*)(ldsc + (BUF) * 49152 + 32768 + (rBb + (N) * 16) * 128 + (((KK) * 64 + ck) ^ sw)))

    f32x4 acc[4][4];
#pragma unroll
    for (int m = 0; m < 4; ++m)
#pragma unroll
        for (int n = 0; n < 4; ++n) acc[m][n] = (f32x4){0.f, 0.f, 0.f, 0.f};

#define GEMM_ITER(T, WAITER) do { \
    int stb_ = cur + 2; if (stb_ >= 3) stb_ -= 3; \
    bf16x8 af[4][2], bfr[4][2]; \
    _Pragma("unroll") for (int m_ = 0; m_ < 4; ++m_) { \
        af[m_][0] = RD_A(cur, m_, 0); af[m_][1] = RD_A(cur, m_, 1); } \
    _Pragma("unroll") for (int n_ = 0; n_ < 4; ++n_) { \
        bfr[n_][0] = RD_B(cur, n_, 0); bfr[n_][1] = RD_B(cur, n_, 1); } \
    if ((T) + 2 < KTILES) { \
        STAGE_AS(stb_, 0, (T) + 2); STAGE_AS(stb_, 1, (T) + 2); \
        STAGE_AS(stb_, 2, (T) + 2); STAGE_AS(stb_, 3, (T) + 2); \
        STAGE_BS(stb_, 0, (T) + 2); STAGE_BS(stb_, 1, (T) + 2); \
    } \
    SP(1); \
    _Pragma("unroll") for (int kk_ = 0; kk_ < 2; ++kk_) \
    _Pragma("unroll") for (int m_ = 0; m_ < 4; ++m_) \
    _Pragma("unroll") for (int n_ = 0; n_ < 4; ++n_) \
        acc[m_][n_] = __builtin_amdgcn_mfma_f32_16x16x32_bf16( \
            af[m_][kk_], bfr[n_][kk_], acc[m_][n_], 0, 0, 0); \
    SP(0); \
    WAITER; \
    BARR(); \
    cur = cur + 1; if (cur >= 3) cur = 0; \
} while (0)

#define BLEND_STEP(G) do { \
    const unsigned idx_ = (unsigned)(G) * 131072u + (unsigned)blockIdx.x * 512u + (unsigned)tid; \
    const unsigned off_ = idx_ << 2; \
    const float* bs_ = Wnext + off_; \
    float4 s_ = make_float4(0.f, 0.f, 0.f, 0.f); \
    _Pragma("unroll") for (int e_ = 0; e_ < 8; ++e_) { \
        float4 v_ = *(const float4*)(bs_ + (size_t)e_ * PER_LAYER); \
        s_.x += cw[e_] * v_.x; s_.y += cw[e_] * v_.y; \
        s_.z += cw[e_] * v_.z; s_.w += cw[e_] * v_.w; } \
    ushort4 o_; \
    o_.x = f2bf(s_.x); o_.y = f2bf(s_.y); o_.z = f2bf(s_.z); o_.w = f2bf(s_.w); \
    *(ushort4*)(wbNext + off_) = o_; \
} while (0)

    STAGE_AS(0, 0, 0); STAGE_AS(0, 1, 0); STAGE_AS(0, 2, 0); STAGE_AS(0, 3, 0);
    STAGE_BS(0, 0, 0); STAGE_BS(0, 1, 0);
    STAGE_AS(1, 0, 1); STAGE_AS(1, 1, 1); STAGE_AS(1, 2, 1); STAGE_AS(1, 3, 1);
    STAGE_BS(1, 0, 1); STAGE_BS(1, 1, 1);
    VMC(6);
    BARR();

    int cur = 0;
    if (BLEND) {
#pragma unroll 1
        for (int g = 0; g < 8; ++g) {
            GEMM_ITER(3 * g, VMC(6));
            BLEND_STEP(g);
            GEMM_ITER(3 * g + 1, VMC(15));
            GEMM_ITER(3 * g + 2, VMC(6));
        }
#pragma unroll 1
        for (int t = 24; t < 30; ++t) GEMM_ITER(t, VMC(6));
    } else {
#pragma unroll 1
        for (int t = 0; t < 30; ++t) GEMM_ITER(t, VMC(6));
    }
    GEMM_ITER(30, VMC(0));
    GEMM_ITER(31, VMC(0));

    const int crow = (lane >> 4) * 4;
    const int ccol = lane & 15;
#pragma unroll
    for (int m = 0; m < 4; ++m)
#pragma unroll
        for (int n = 0; n < 4; ++n) {
            const size_t col = blockN + wc * 64 + n * 16 + ccol;
            const float bv = bias[col];
#pragma unroll
            for (int r = 0; r < 4; ++r) {
                const size_t row = blockM + wr * 64 + m * 16 + crow + r;
                float v = acc[m][n][r] + bv;
                if (ACT) v = v > 0.f ? v : expm1f(v);
                if constexpr (sizeof(OutT) == 2) {
                    C[row * NDIM + col] = (OutT)f2bf(v);
                } else {
                    C[row * NDIM + col] = (OutT)v;
                }
            }
        }
#undef STAGE_AS
#undef STAGE_BS
#undef RD_A
#undef RD_B
#undef GEMM_ITER
#undef BLEND_STEP
}

// ---------------------------------------------------------------------------
// Launch: blend0 (W0 only), then GEMM0 (A = x f32, fused convert + W1 blend),
// GEMM1 (fused W2 blend), GEMM2 plain.
// Workspace (ushort units): wb0, wb1, wb2 [PER_LAYER each], y0, y1 [8388608].
// ---------------------------------------------------------------------------
extern "C" void kernel_launch(void* const* d_in, const int* in_sizes, int n_in,
                              void* d_out, int out_size, void* d_ws, size_t ws_size,
                              hipStream_t stream) {
    const float* blendw = (const float*)d_in[0];   // (8,)
    const float* x      = (const float*)d_in[1];   // (4096, 2048)
    const float* W      = (const float*)d_in[2];   // (3, 8, 2048, 2048)
    const float* Bb     = (const float*)d_in[3];   // (3, 2048)
    float* out = (float*)d_out;                    // (4096, 2048) f32

    unsigned short* wb0 = (unsigned short*)d_ws;
    unsigned short* wb1 = wb0 + PER_LAYER;
    unsigned short* wb2 = wb1 + PER_LAYER;
    unsigned short* y0  = wb2 + PER_LAYER;
    unsigned short* y1  = y0 + 8388608;

    blend0_kernel<<<2048, 256, 0, stream>>>(W, blendw, wb0);

    const int grid = (MDIM / 256) * (NDIM / 128);    // 256 blocks = all CUs
    gemm_x32<1, unsigned short><<<grid, 512, 0, stream>>>(
        x, wb0, Bb, y0, W + (size_t)8 * PER_LAYER, blendw, wb1);
    gemm_fused<1, unsigned short, 1><<<grid, 512, 0, stream>>>(
        y0, wb1, Bb + 2048, y1, W + (size_t)16 * PER_LAYER, blendw, wb2);
    gemm_fused<0, float, 0><<<grid, 512, 0, stream>>>(
        y1, wb2, Bb + 4096, out, nullptr, nullptr, nullptr);
}

// Round 14
// 204.353 us; speedup vs baseline: 1.2149x; 1.1181x over previous
//
#include <hip/hip_runtime.h>
#include <hip/hip_bf16.h>

// Problem dims (fixed by reference): E=8, D=2048, B=4096, 3 layers.
#define MDIM 4096
#define NDIM 2048
#define KDIM 2048
#define KTILES 32          // K / 64
#define PER_LAYER 4194304  // 2048*2048

typedef __attribute__((ext_vector_type(8))) short bf16x8;   // 8 bf16 (4 VGPRs)
typedef __attribute__((ext_vector_type(4))) float f32x4;    // MFMA accumulator

__device__ __forceinline__ unsigned short f2bf(float f) {
    unsigned u = __builtin_bit_cast(unsigned, f);
    u += 0x7FFFu + ((u >> 16) & 1u);        // round-to-nearest-even
    return (unsigned short)(u >> 16);
}

// ---------------------------------------------------------------------------
// Kernel 1: blend layer-0 experts + convert x to bf16 (W1/W2 blend is fused
// into the GEMM kernels). Reads 134MB W0 + 32MB x -> ~30us HBM-bound.
// ---------------------------------------------------------------------------
__global__ __launch_bounds__(256) void blend0_kernel(
    const float* __restrict__ W, const float* __restrict__ cb,
    const float* __restrict__ x,
    unsigned short* __restrict__ wb, unsigned short* __restrict__ xb)
{
    float c[8];
#pragma unroll
    for (int e = 0; e < 8; ++e) c[e] = cb[e];
    const unsigned wtotal4 = PER_LAYER >> 2;        // 1,048,576 float4 units
    const unsigned xtotal4 = 2097152u;              // 8M / 4
    const unsigned total = wtotal4 + xtotal4;
    unsigned stride = gridDim.x * blockDim.x;
    for (unsigned i = blockIdx.x * blockDim.x + threadIdx.x; i < total; i += stride) {
        if (i < wtotal4) {
            unsigned off = i << 2;
            const float* base = W + off;
            float4 s = make_float4(0.f, 0.f, 0.f, 0.f);
#pragma unroll
            for (int e = 0; e < 8; ++e) {
                float4 v = *(const float4*)(base + (size_t)e * PER_LAYER);
                s.x += c[e] * v.x; s.y += c[e] * v.y;
                s.z += c[e] * v.z; s.w += c[e] * v.w;
            }
            ushort4 o;
            o.x = f2bf(s.x); o.y = f2bf(s.y); o.z = f2bf(s.z); o.w = f2bf(s.w);
            *(ushort4*)(wb + off) = o;
        } else {
            unsigned j = (i - wtotal4) << 2;
            float4 v = *(const float4*)(x + j);
            ushort4 o;
            o.x = f2bf(v.x); o.y = f2bf(v.y); o.z = f2bf(v.z); o.w = f2bf(v.w);
            *(ushort4*)(xb + j) = o;
        }
    }
}

// ---------------------------------------------------------------------------
// Kernel 2: r7 GEMM (256x128 tile, 3-buf LDS 144KB, 2-tile-deep prefetch,
// 1 barrier per K-tile) + OPTIONAL fused blend of the NEXT layer's weights.
//   C[M,N] = A[M,K] * Bw[N,K]^T + bias, optional ELU;  wbNext = sum_e c_e W_e.
// grid = 256 blocks (all CUs), 512 threads = 8 waves (4M x 2N), wave 64x64.
// Blend: on iters t=0,3,..,21 each thread blends ONE float4 of W_next
// (8x16B loads + 1 store = 9 vmem ops) issued AFTER the end-of-iter barrier.
// vmcnt ledger (FIFO, per wave):
//   t%3==0: outstanding stage(t+1)6 + stage(t+2)6 -> VMC(6) drains t+1; blend after.
//   t%3==1: outstanding stage(t+2)6 + blend9 + stage(t+3)6; younger-than-
//           stage(t+2) = 15 -> VMC(15) drains t+2.
//   t%3==2: VMC(6) (also drains the old blend ops).
// BLEND=0 uses VMC(6) everywhere.
// WAR: stage target buf (t+2)%3 last read iter t-1, barrier-separated.
// ---------------------------------------------------------------------------
#define BARR() do { asm volatile("" ::: "memory"); __builtin_amdgcn_s_barrier(); asm volatile("" ::: "memory"); } while (0)
#define SP(N) __builtin_amdgcn_s_setprio(N)
#define VMC_IMPL(N) asm volatile("s_waitcnt vmcnt(" #N ")" ::: "memory")
#define VMC(N) VMC_IMPL(N)

template<int ACT, typename OutT, int BLEND>
__global__ __launch_bounds__(512, 2) void gemm_fused(
    const unsigned short* __restrict__ A,   // M x K bf16 bits
    const unsigned short* __restrict__ Bw,  // N x K bf16 bits
    const float* __restrict__ bias,         // N
    OutT* __restrict__ C,                   // M x N
    const float* __restrict__ Wnext,        // 8 x 2048 x 2048 f32 (or null)
    const float* __restrict__ cb,           // (8,) blend coeffs (or null)
    unsigned short* __restrict__ wbNext)    // 2048 x 2048 bf16 out (or null)
{
    __shared__ __align__(16) unsigned short lds[73728];   // 144 KB
    char* ldsc = (char*)lds;

    const int tid = threadIdx.x;
    const int wid = tid >> 6;
    const int lane = tid & 63;
    const int wr = wid >> 1;      // 0..3 (M)
    const int wc = wid & 1;       // 0..1 (N)

    // blend coeffs: load + fence BEFORE any counted vmem ops.
    float cw[8];
    if (BLEND) {
#pragma unroll
        for (int e = 0; e < 8; ++e) cw[e] = cb[e];
        VMC(0);
    }

    // bijective XCD-chunked swizzle: XCD k gets wg in [k*32,(k+1)*32)
    // = 2 N-panels x 16 M-tiles -> B panels (1MB) L2-resident per XCD.
    const int wg = (blockIdx.x & 7) * 32 + (blockIdx.x >> 3);
    const size_t blockM = (size_t)(wg & 15) * 256;
    const size_t blockN = (size_t)(wg >> 4) * 128;

    // ds_read addressing: swizzled 16B slot within a 128B row.
    const int sw = (lane & 7) << 4;          // (row&7)<<4; row&7 == lane&7
    const int ck = (lane >> 4) << 4;         // k-slot byte base
    const int rAb = wr * 64 + (lane & 15);   // + m*16
    const int rBb = wc * 64 + (lane & 15);   // + n*16

    // staging: thread t writes LDS bytes [tid*16, tid*16+16) of an 8KB
    // 64-row stage; source column pre-XORed (both-sides swizzle).
    const int srow = tid >> 3;                       // 0..63
    const int scol = ((tid & 7) ^ (srow & 7)) << 3;  // element offset
    const unsigned short* aStage = A + (blockM + srow) * KDIM + scol;
    const unsigned short* bStage = Bw + (blockN + srow) * KDIM + scol;

#define STAGE_AS(BUF, S, KT) do { \
    const unsigned short* g_ = aStage + (size_t)(S) * 64 * KDIM + (size_t)(KT) * 64; \
    __builtin_amdgcn_global_load_lds((const __attribute__((address_space(1))) void*)g_, \
        (__attribute__((address_space(3))) void*)(ldsc + (BUF) * 49152 + (S) * 8192 + tid * 16), \
        16, 0, 0); \
} while (0)

#define STAGE_BS(BUF, S, KT) do { \
    const unsigned short* g_ = bStage + (size_t)(S) * 64 * KDIM + (size_t)(KT) * 64; \
    __builtin_amdgcn_global_load_lds((const __attribute__((address_space(1))) void*)g_, \
        (__attribute__((address_space(3))) void*)(ldsc + (BUF) * 49152 + 32768 + (S) * 8192 + tid * 16), \
        16, 0, 0); \
} while (0)

#define RD_A(BUF, M, KK) \
    (*(const bf16x8*)(ldsc + (BUF) * 49152 + ((rAb + (M) * 16)) * 128 + (((KK) * 64 + ck) ^ sw)))
#define RD_B(BUF, N, KK) \
    (*(const bf16x8*)(ldsc + (BUF) * 49152 + 32768 + (rBb + (N) * 16) * 128 + (((KK) * 64 + ck) ^ sw)))

    f32x4 acc[4][4];
#pragma unroll
    for (int m = 0; m < 4; ++m)
#pragma unroll
        for (int n = 0; n < 4; ++n) acc[m][n] = (f32x4){0.f, 0.f, 0.f, 0.f};

    // One GEMM K-iteration: reads tile in buf `cur`, stages tile t+2 into
    // buf (cur+2)%3, MFMAs, then WAITER, barrier, advances cur.
#define GEMM_ITER(T, WAITER) do { \
    int stb_ = cur + 2; if (stb_ >= 3) stb_ -= 3; \
    bf16x8 af[4][2], bfr[4][2]; \
    _Pragma("unroll") for (int m_ = 0; m_ < 4; ++m_) { \
        af[m_][0] = RD_A(cur, m_, 0); af[m_][1] = RD_A(cur, m_, 1); } \
    _Pragma("unroll") for (int n_ = 0; n_ < 4; ++n_) { \
        bfr[n_][0] = RD_B(cur, n_, 0); bfr[n_][1] = RD_B(cur, n_, 1); } \
    if ((T) + 2 < KTILES) { \
        STAGE_AS(stb_, 0, (T) + 2); STAGE_AS(stb_, 1, (T) + 2); \
        STAGE_AS(stb_, 2, (T) + 2); STAGE_AS(stb_, 3, (T) + 2); \
        STAGE_BS(stb_, 0, (T) + 2); STAGE_BS(stb_, 1, (T) + 2); \
    } \
    SP(1); \
    _Pragma("unroll") for (int kk_ = 0; kk_ < 2; ++kk_) \
    _Pragma("unroll") for (int m_ = 0; m_ < 4; ++m_) \
    _Pragma("unroll") for (int n_ = 0; n_ < 4; ++n_) \
        acc[m_][n_] = __builtin_amdgcn_mfma_f32_16x16x32_bf16( \
            af[m_][kk_], bfr[n_][kk_], acc[m_][n_], 0, 0, 0); \
    SP(0); \
    WAITER; \
    BARR(); \
    cur = cur + 1; if (cur >= 3) cur = 0; \
} while (0)

    // one blend chunk: this thread blends float4 #(G*131072 + bid*512 + tid)
#define BLEND_STEP(G) do { \
    const unsigned idx_ = (unsigned)(G) * 131072u + (unsigned)blockIdx.x * 512u + (unsigned)tid; \
    const unsigned off_ = idx_ << 2; \
    const float* bs_ = Wnext + off_; \
    float4 s_ = make_float4(0.f, 0.f, 0.f, 0.f); \
    _Pragma("unroll") for (int e_ = 0; e_ < 8; ++e_) { \
        float4 v_ = *(const float4*)(bs_ + (size_t)e_ * PER_LAYER); \
        s_.x += cw[e_] * v_.x; s_.y += cw[e_] * v_.y; \
        s_.z += cw[e_] * v_.z; s_.w += cw[e_] * v_.w; } \
    ushort4 o_; \
    o_.x = f2bf(s_.x); o_.y = f2bf(s_.y); o_.z = f2bf(s_.z); o_.w = f2bf(s_.w); \
    *(ushort4*)(wbNext + off_) = o_; \
} while (0)

    // ---- prologue: tile0 -> buf0, tile1 -> buf1 ----
    STAGE_AS(0, 0, 0); STAGE_AS(0, 1, 0); STAGE_AS(0, 2, 0); STAGE_AS(0, 3, 0);
    STAGE_BS(0, 0, 0); STAGE_BS(0, 1, 0);
    STAGE_AS(1, 0, 1); STAGE_AS(1, 1, 1); STAGE_AS(1, 2, 1); STAGE_AS(1, 3, 1);
    STAGE_BS(1, 0, 1); STAGE_BS(1, 1, 1);
    VMC(6);                       // tile0 landed; tile1's 6 in flight
    BARR();

    int cur = 0;
    if (BLEND) {
#pragma unroll 1
        for (int g = 0; g < 8; ++g) {
            GEMM_ITER(3 * g, VMC(6));
            BLEND_STEP(g);                     // 9 vmem ops at start of iter 3g+1
            GEMM_ITER(3 * g + 1, VMC(15));     // drain S(3g+2); keep blend+S(3g+3)
            GEMM_ITER(3 * g + 2, VMC(6));      // drains blend + S(3g+3)
        }
#pragma unroll 1
        for (int t = 24; t < 30; ++t) GEMM_ITER(t, VMC(6));
    } else {
#pragma unroll 1
        for (int t = 0; t < 30; ++t) GEMM_ITER(t, VMC(6));
    }
    GEMM_ITER(30, VMC(0));        // stages nothing; drains S(31)
    GEMM_ITER(31, VMC(0));        // final tile

    // ---- epilogue: C/D layout col=lane&15 (N), row=(lane>>4)*4+reg (M) ----
    const int crow = (lane >> 4) * 4;
    const int ccol = lane & 15;
#pragma unroll
    for (int m = 0; m < 4; ++m)
#pragma unroll
        for (int n = 0; n < 4; ++n) {
            const size_t col = blockN + wc * 64 + n * 16 + ccol;
            const float bv = bias[col];
#pragma unroll
            for (int r = 0; r < 4; ++r) {
                const size_t row = blockM + wr * 64 + m * 16 + crow + r;
                float v = acc[m][n][r] + bv;
                if (ACT) v = v > 0.f ? v : expm1f(v);
                if constexpr (sizeof(OutT) == 2) {
                    C[row * NDIM + col] = (OutT)f2bf(v);
                } else {
                    C[row * NDIM + col] = (OutT)v;
                }
            }
        }
#undef STAGE_AS
#undef STAGE_BS
#undef RD_A
#undef RD_B
#undef GEMM_ITER
#undef BLEND_STEP
}

// ---------------------------------------------------------------------------
// Launch: blend0+convert, then 3 chained GEMMs; GEMM0 blends W1, GEMM1
// blends W2 (overlapped with compute), GEMM2 plain.
// Workspace (ushort units): wb[3*PER_LAYER] weights, xb[8388608], y0[8388608].
// ---------------------------------------------------------------------------
extern "C" void kernel_launch(void* const* d_in, const int* in_sizes, int n_in,
                              void* d_out, int out_size, void* d_ws, size_t ws_size,
                              hipStream_t stream) {
    const float* blendw = (const float*)d_in[0];   // (8,)
    const float* x      = (const float*)d_in[1];   // (4096, 2048)
    const float* W      = (const float*)d_in[2];   // (3, 8, 2048, 2048)
    const float* Bb     = (const float*)d_in[3];   // (3, 2048)
    float* out = (float*)d_out;                    // (4096, 2048) f32

    unsigned short* wb0 = (unsigned short*)d_ws;
    unsigned short* wb1 = wb0 + PER_LAYER;
    unsigned short* wb2 = wb1 + PER_LAYER;
    unsigned short* xb  = wb2 + PER_LAYER;
    unsigned short* y0  = xb + 8388608;
    unsigned short* y1  = xb;   // reuse: xb dead after GEMM0

    blend0_kernel<<<2048, 256, 0, stream>>>(W, blendw, x, wb0, xb);

    const int grid = (MDIM / 256) * (NDIM / 128);    // 256 blocks = all CUs
    gemm_fused<1, unsigned short, 1><<<grid, 512, 0, stream>>>(
        xb, wb0, Bb,        y0,  W + (size_t)8 * PER_LAYER,  blendw, wb1);
    gemm_fused<1, unsigned short, 1><<<grid, 512, 0, stream>>>(
        y0, wb1, Bb + 2048, y1,  W + (size_t)16 * PER_LAYER, blendw, wb2);
    gemm_fused<0, float, 0><<<grid, 512, 0, stream>>>(
        y1, wb2, Bb + 4096, out, nullptr, nullptr, nullptr);
}

// Round 15
// 196.954 us; speedup vs baseline: 1.2606x; 1.0376x over previous
//
#include <hip/hip_runtime.h>
#include <hip/hip_bf16.h>

// Problem dims (fixed by reference): E=8, D=2048, B=4096, 3 layers.
#define MDIM 4096
#define NDIM 2048
#define KDIM 2048
#define KTILES 32          // K / 64
#define PER_LAYER 4194304  // 2048*2048

typedef __attribute__((ext_vector_type(8))) short bf16x8;   // 8 bf16 (4 VGPRs)
typedef __attribute__((ext_vector_type(4))) float f32x4;    // MFMA accumulator

__device__ __forceinline__ unsigned short f2bf(float f) {
    unsigned u = __builtin_bit_cast(unsigned, f);
    u += 0x7FFFu + ((u >> 16) & 1u);        // round-to-nearest-even
    return (unsigned short)(u >> 16);
}

// fast ELU negative branch: exp(v)-1 via v_exp_f32; bf16 output rounding
// (2^-8 rel) dwarfs the exp approximation error vs expm1f.
__device__ __forceinline__ float fast_elu_neg(float v) {
    return __expf(v) - 1.0f;
}

// ---------------------------------------------------------------------------
// Kernel 1: blend layer-0 experts + convert x to bf16 (W1/W2 blend is fused
// into the GEMM kernels). Reads 134MB W0 + 32MB x -> ~30us HBM-bound.
// ---------------------------------------------------------------------------
__global__ __launch_bounds__(256) void blend0_kernel(
    const float* __restrict__ W, const float* __restrict__ cb,
    const float* __restrict__ x,
    unsigned short* __restrict__ wb, unsigned short* __restrict__ xb)
{
    float c[8];
#pragma unroll
    for (int e = 0; e < 8; ++e) c[e] = cb[e];
    const unsigned wtotal4 = PER_LAYER >> 2;        // 1,048,576 float4 units
    const unsigned xtotal4 = 2097152u;              // 8M / 4
    const unsigned total = wtotal4 + xtotal4;
    unsigned stride = gridDim.x * blockDim.x;
    for (unsigned i = blockIdx.x * blockDim.x + threadIdx.x; i < total; i += stride) {
        if (i < wtotal4) {
            unsigned off = i << 2;
            const float* base = W + off;
            float4 s = make_float4(0.f, 0.f, 0.f, 0.f);
#pragma unroll
            for (int e = 0; e < 8; ++e) {
                float4 v = *(const float4*)(base + (size_t)e * PER_LAYER);
                s.x += c[e] * v.x; s.y += c[e] * v.y;
                s.z += c[e] * v.z; s.w += c[e] * v.w;
            }
            ushort4 o;
            o.x = f2bf(s.x); o.y = f2bf(s.y); o.z = f2bf(s.z); o.w = f2bf(s.w);
            *(ushort4*)(wb + off) = o;
        } else {
            unsigned j = (i - wtotal4) << 2;
            float4 v = *(const float4*)(x + j);
            ushort4 o;
            o.x = f2bf(v.x); o.y = f2bf(v.y); o.z = f2bf(v.z); o.w = f2bf(v.w);
            *(ushort4*)(xb + j) = o;
        }
    }
}

// ---------------------------------------------------------------------------
// Kernel 2: r7 GEMM (256x128 tile, 3-buf LDS 144KB, 2-tile-deep prefetch,
// 1 barrier per K-tile) + OPTIONAL fused blend of the NEXT layer's weights.
//   C[M,N] = A[M,K] * Bw[N,K]^T + bias, optional ELU;  wbNext = sum_e c_e W_e.
// grid = 256 blocks (all CUs), 512 threads = 8 waves (4M x 2N), wave 64x64.
// Blend: on iters t=0,3,..,21 each thread blends ONE float4 of W_next
// (8x16B loads + 1 store = 9 vmem ops) issued AFTER the end-of-iter barrier.
// vmcnt ledger (FIFO, per wave):
//   t%3==0: outstanding stage(t+1)6 + stage(t+2)6 -> VMC(6) drains t+1; blend after.
//   t%3==1: outstanding stage(t+2)6 + blend9 + stage(t+3)6; younger-than-
//           stage(t+2) = 15 -> VMC(15) drains t+2.
//   t%3==2: VMC(6) (also drains the old blend ops).
// BLEND=0 uses VMC(6) everywhere.
// WAR: stage target buf (t+2)%3 last read iter t-1, barrier-separated.
// ---------------------------------------------------------------------------
#define BARR() do { asm volatile("" ::: "memory"); __builtin_amdgcn_s_barrier(); asm volatile("" ::: "memory"); } while (0)
#define SP(N) __builtin_amdgcn_s_setprio(N)
#define VMC_IMPL(N) asm volatile("s_waitcnt vmcnt(" #N ")" ::: "memory")
#define VMC(N) VMC_IMPL(N)

template<int ACT, typename OutT, int BLEND>
__global__ __launch_bounds__(512, 2) void gemm_fused(
    const unsigned short* __restrict__ A,   // M x K bf16 bits
    const unsigned short* __restrict__ Bw,  // N x K bf16 bits
    const float* __restrict__ bias,         // N
    OutT* __restrict__ C,                   // M x N
    const float* __restrict__ Wnext,        // 8 x 2048 x 2048 f32 (or null)
    const float* __restrict__ cb,           // (8,) blend coeffs (or null)
    unsigned short* __restrict__ wbNext)    // 2048 x 2048 bf16 out (or null)
{
    __shared__ __align__(16) unsigned short lds[73728];   // 144 KB
    char* ldsc = (char*)lds;

    const int tid = threadIdx.x;
    const int wid = tid >> 6;
    const int lane = tid & 63;
    const int wr = wid >> 1;      // 0..3 (M)
    const int wc = wid & 1;       // 0..1 (N)

    // blend coeffs: load + fence BEFORE any counted vmem ops.
    float cw[8];
    if (BLEND) {
#pragma unroll
        for (int e = 0; e < 8; ++e) cw[e] = cb[e];
        VMC(0);
    }

    // bijective XCD-chunked swizzle: XCD k gets wg in [k*32,(k+1)*32)
    // = 2 N-panels x 16 M-tiles -> B panels (1MB) L2-resident per XCD.
    const int wg = (blockIdx.x & 7) * 32 + (blockIdx.x >> 3);
    const size_t blockM = (size_t)(wg & 15) * 256;
    const size_t blockN = (size_t)(wg >> 4) * 128;

    // ds_read addressing: swizzled 16B slot within a 128B row.
    const int sw = (lane & 7) << 4;          // (row&7)<<4; row&7 == lane&7
    const int ck = (lane >> 4) << 4;         // k-slot byte base
    const int rAb = wr * 64 + (lane & 15);   // + m*16
    const int rBb = wc * 64 + (lane & 15);   // + n*16

    // staging: thread t writes LDS bytes [tid*16, tid*16+16) of an 8KB
    // 64-row stage; source column pre-XORed (both-sides swizzle).
    const int srow = tid >> 3;                       // 0..63
    const int scol = ((tid & 7) ^ (srow & 7)) << 3;  // element offset
    const unsigned short* aStage = A + (blockM + srow) * KDIM + scol;
    const unsigned short* bStage = Bw + (blockN + srow) * KDIM + scol;

#define STAGE_AS(BUF, S, KT) do { \
    const unsigned short* g_ = aStage + (size_t)(S) * 64 * KDIM + (size_t)(KT) * 64; \
    __builtin_amdgcn_global_load_lds((const __attribute__((address_space(1))) void*)g_, \
        (__attribute__((address_space(3))) void*)(ldsc + (BUF) * 49152 + (S) * 8192 + tid * 16), \
        16, 0, 0); \
} while (0)

#define STAGE_BS(BUF, S, KT) do { \
    const unsigned short* g_ = bStage + (size_t)(S) * 64 * KDIM + (size_t)(KT) * 64; \
    __builtin_amdgcn_global_load_lds((const __attribute__((address_space(1))) void*)g_, \
        (__attribute__((address_space(3))) void*)(ldsc + (BUF) * 49152 + 32768 + (S) * 8192 + tid * 16), \
        16, 0, 0); \
} while (0)

#define RD_A(BUF, M, KK) \
    (*(const bf16x8*)(ldsc + (BUF) * 49152 + ((rAb + (M) * 16)) * 128 + (((KK) * 64 + ck) ^ sw)))
#define RD_B(BUF, N, KK) \
    (*(const bf16x8*)(ldsc + (BUF) * 49152 + 32768 + (rBb + (N) * 16) * 128 + (((KK) * 64 + ck) ^ sw)))

    f32x4 acc[4][4];
#pragma unroll
    for (int m = 0; m < 4; ++m)
#pragma unroll
        for (int n = 0; n < 4; ++n) acc[m][n] = (f32x4){0.f, 0.f, 0.f, 0.f};

    // One GEMM K-iteration: reads tile in buf `cur`, stages tile t+2 into
    // buf (cur+2)%3, MFMAs, then WAITER, barrier, advances cur.
#define GEMM_ITER(T, WAITER) do { \
    int stb_ = cur + 2; if (stb_ >= 3) stb_ -= 3; \
    bf16x8 af[4][2], bfr[4][2]; \
    _Pragma("unroll") for (int m_ = 0; m_ < 4; ++m_) { \
        af[m_][0] = RD_A(cur, m_, 0); af[m_][1] = RD_A(cur, m_, 1); } \
    _Pragma("unroll") for (int n_ = 0; n_ < 4; ++n_) { \
        bfr[n_][0] = RD_B(cur, n_, 0); bfr[n_][1] = RD_B(cur, n_, 1); } \
    if ((T) + 2 < KTILES) { \
        STAGE_AS(stb_, 0, (T) + 2); STAGE_AS(stb_, 1, (T) + 2); \
        STAGE_AS(stb_, 2, (T) + 2); STAGE_AS(stb_, 3, (T) + 2); \
        STAGE_BS(stb_, 0, (T) + 2); STAGE_BS(stb_, 1, (T) + 2); \
    } \
    SP(1); \
    _Pragma("unroll") for (int kk_ = 0; kk_ < 2; ++kk_) \
    _Pragma("unroll") for (int m_ = 0; m_ < 4; ++m_) \
    _Pragma("unroll") for (int n_ = 0; n_ < 4; ++n_) \
        acc[m_][n_] = __builtin_amdgcn_mfma_f32_16x16x32_bf16( \
            af[m_][kk_], bfr[n_][kk_], acc[m_][n_], 0, 0, 0); \
    SP(0); \
    WAITER; \
    BARR(); \
    cur = cur + 1; if (cur >= 3) cur = 0; \
} while (0)

    // one blend chunk: this thread blends float4 #(G*131072 + bid*512 + tid)
#define BLEND_STEP(G) do { \
    const unsigned idx_ = (unsigned)(G) * 131072u + (unsigned)blockIdx.x * 512u + (unsigned)tid; \
    const unsigned off_ = idx_ << 2; \
    const float* bs_ = Wnext + off_; \
    float4 s_ = make_float4(0.f, 0.f, 0.f, 0.f); \
    _Pragma("unroll") for (int e_ = 0; e_ < 8; ++e_) { \
        float4 v_ = *(const float4*)(bs_ + (size_t)e_ * PER_LAYER); \
        s_.x += cw[e_] * v_.x; s_.y += cw[e_] * v_.y; \
        s_.z += cw[e_] * v_.z; s_.w += cw[e_] * v_.w; } \
    ushort4 o_; \
    o_.x = f2bf(s_.x); o_.y = f2bf(s_.y); o_.z = f2bf(s_.z); o_.w = f2bf(s_.w); \
    *(ushort4*)(wbNext + off_) = o_; \
} while (0)

    // ---- prologue: tile0 -> buf0, tile1 -> buf1 ----
    STAGE_AS(0, 0, 0); STAGE_AS(0, 1, 0); STAGE_AS(0, 2, 0); STAGE_AS(0, 3, 0);
    STAGE_BS(0, 0, 0); STAGE_BS(0, 1, 0);
    STAGE_AS(1, 0, 1); STAGE_AS(1, 1, 1); STAGE_AS(1, 2, 1); STAGE_AS(1, 3, 1);
    STAGE_BS(1, 0, 1); STAGE_BS(1, 1, 1);
    VMC(6);                       // tile0 landed; tile1's 6 in flight
    BARR();

    int cur = 0;
    if (BLEND) {
#pragma unroll 1
        for (int g = 0; g < 8; ++g) {
            GEMM_ITER(3 * g, VMC(6));
            BLEND_STEP(g);                     // 9 vmem ops at start of iter 3g+1
            GEMM_ITER(3 * g + 1, VMC(15));     // drain S(3g+2); keep blend+S(3g+3)
            GEMM_ITER(3 * g + 2, VMC(6));      // drains blend + S(3g+3)
        }
#pragma unroll 1
        for (int t = 24; t < 30; ++t) GEMM_ITER(t, VMC(6));
    } else {
#pragma unroll 1
        for (int t = 0; t < 30; ++t) GEMM_ITER(t, VMC(6));
    }
    GEMM_ITER(30, VMC(0));        // stages nothing; drains S(31)
    GEMM_ITER(31, VMC(0));        // final tile

    // ---- epilogue: C/D layout col=lane&15 (N), row=(lane>>4)*4+reg (M) ----
    const int crow = (lane >> 4) * 4;
    const int ccol = lane & 15;
#pragma unroll
    for (int m = 0; m < 4; ++m)
#pragma unroll
        for (int n = 0; n < 4; ++n) {
            const size_t col = blockN + wc * 64 + n * 16 + ccol;
            const float bv = bias[col];
#pragma unroll
            for (int r = 0; r < 4; ++r) {
                const size_t row = blockM + wr * 64 + m * 16 + crow + r;
                float v = acc[m][n][r] + bv;
                if (ACT) v = v > 0.f ? v : fast_elu_neg(v);
                if constexpr (sizeof(OutT) == 2) {
                    C[row * NDIM + col] = (OutT)f2bf(v);
                } else {
                    C[row * NDIM + col] = (OutT)v;
                }
            }
        }
#undef STAGE_AS
#undef STAGE_BS
#undef RD_A
#undef RD_B
#undef GEMM_ITER
#undef BLEND_STEP
}

// ---------------------------------------------------------------------------
// Launch: blend0+convert, then 3 chained GEMMs; GEMM0 blends W1, GEMM1
// blends W2 (overlapped with compute), GEMM2 plain.
// Workspace (ushort units): wb[3*PER_LAYER] weights, xb[8388608], y0[8388608].
// ---------------------------------------------------------------------------
extern "C" void kernel_launch(void* const* d_in, const int* in_sizes, int n_in,
                              void* d_out, int out_size, void* d_ws, size_t ws_size,
                              hipStream_t stream) {
    const float* blendw = (const float*)d_in[0];   // (8,)
    const float* x      = (const float*)d_in[1];   // (4096, 2048)
    const float* W      = (const float*)d_in[2];   // (3, 8, 2048, 2048)
    const float* Bb     = (const float*)d_in[3];   // (3, 2048)
    float* out = (float*)d_out;                    // (4096, 2048) f32

    unsigned short* wb0 = (unsigned short*)d_ws;
    unsigned short* wb1 = wb0 + PER_LAYER;
    unsigned short* wb2 = wb1 + PER_LAYER;
    unsigned short* xb  = wb2 + PER_LAYER;
    unsigned short* y0  = xb + 8388608;
    unsigned short* y1  = xb;   // reuse: xb dead after GEMM0

    blend0_kernel<<<2048, 256, 0, stream>>>(W, blendw, x, wb0, xb);

    const int grid = (MDIM / 256) * (NDIM / 128);    // 256 blocks = all CUs
    gemm_fused<1, unsigned short, 1><<<grid, 512, 0, stream>>>(
        xb, wb0, Bb,        y0,  W + (size_t)8 * PER_LAYER,  blendw, wb1);
    gemm_fused<1, unsigned short, 1><<<grid, 512, 0, stream>>>(
        y0, wb1, Bb + 2048, y1,  W + (size_t)16 * PER_LAYER, blendw, wb2);
    gemm_fused<0, float, 0><<<grid, 512, 0, stream>>>(
        y1, wb2, Bb + 4096, out, nullptr, nullptr, nullptr);
}

// Round 16
// 191.781 us; speedup vs baseline: 1.2946x; 1.0270x over previous
//
#include <hip/hip_runtime.h>
#include <hip/hip_bf16.h>

// Problem dims (fixed by reference): E=8, D=2048, B=4096, 3 layers.
#define MDIM 4096
#define NDIM 2048
#define KDIM 2048
#define KTILES 32          // K / 64
#define PER_LAYER 4194304  // 2048*2048

typedef __attribute__((ext_vector_type(8))) short bf16x8;   // 8 bf16 (4 VGPRs)
typedef __attribute__((ext_vector_type(4))) float f32x4;    // MFMA accumulator

__device__ __forceinline__ unsigned short f2bf(float f) {
    unsigned u = __builtin_bit_cast(unsigned, f);
    u += 0x7FFFu + ((u >> 16) & 1u);        // round-to-nearest-even
    return (unsigned short)(u >> 16);
}

// fast ELU negative branch: exp(v)-1 via v_exp_f32; bf16 output rounding
// (2^-8 rel) dwarfs the exp approximation error vs expm1f. (r15: +7.4us)
__device__ __forceinline__ float fast_elu_neg(float v) {
    return __expf(v) - 1.0f;
}

// ---------------------------------------------------------------------------
// Kernel 1: blend layer-0 experts + convert x to bf16 (W1/W2 blend is fused
// into the GEMM kernels). Reads 134MB W0 + 32MB x -> ~30us HBM-bound.
// ---------------------------------------------------------------------------
__global__ __launch_bounds__(256) void blend0_kernel(
    const float* __restrict__ W, const float* __restrict__ cb,
    const float* __restrict__ x,
    unsigned short* __restrict__ wb, unsigned short* __restrict__ xb)
{
    float c[8];
#pragma unroll
    for (int e = 0; e < 8; ++e) c[e] = cb[e];
    const unsigned wtotal4 = PER_LAYER >> 2;        // 1,048,576 float4 units
    const unsigned xtotal4 = 2097152u;              // 8M / 4
    const unsigned total = wtotal4 + xtotal4;
    unsigned stride = gridDim.x * blockDim.x;
    for (unsigned i = blockIdx.x * blockDim.x + threadIdx.x; i < total; i += stride) {
        if (i < wtotal4) {
            unsigned off = i << 2;
            const float* base = W + off;
            float4 s = make_float4(0.f, 0.f, 0.f, 0.f);
#pragma unroll
            for (int e = 0; e < 8; ++e) {
                float4 v = *(const float4*)(base + (size_t)e * PER_LAYER);
                s.x += c[e] * v.x; s.y += c[e] * v.y;
                s.z += c[e] * v.z; s.w += c[e] * v.w;
            }
            ushort4 o;
            o.x = f2bf(s.x); o.y = f2bf(s.y); o.z = f2bf(s.z); o.w = f2bf(s.w);
            *(ushort4*)(wb + off) = o;
        } else {
            unsigned j = (i - wtotal4) << 2;
            float4 v = *(const float4*)(x + j);
            ushort4 o;
            o.x = f2bf(v.x); o.y = f2bf(v.y); o.z = f2bf(v.z); o.w = f2bf(v.w);
            *(ushort4*)(xb + j) = o;
        }
    }
}

// ---------------------------------------------------------------------------
// Kernel 2: r7 GEMM (256x128 tile, 3-buf LDS 144KB, 2-tile-deep prefetch,
// 1 barrier per K-tile) + OPTIONAL fused blend of the NEXT layer's weights.
//   C[M,N] = A[M,K] * Bw[N,K]^T + bias, optional ELU;  wbNext = sum_e c_e W_e.
// grid = 256 blocks (all CUs), 512 threads = 8 waves (4M x 2N), wave 64x64.
// r16: s_setprio removed from the MFMA cluster — m190 measured setprio as
// null-to-negative on barrier-lockstep GEMM structures (T5 needs role-split).
// Blend: on iters t=0,3,..,21 each thread blends ONE float4 of W_next
// (8x16B loads + 1 store = 9 vmem ops) issued AFTER the end-of-iter barrier.
// vmcnt ledger (FIFO, per wave):
//   t%3==0: outstanding stage(t+1)6 + stage(t+2)6 -> VMC(6) drains t+1; blend after.
//   t%3==1: outstanding stage(t+2)6 + blend9 + stage(t+3)6 -> VMC(15) drains t+2.
//   t%3==2: VMC(6) (also drains the old blend ops).
// BLEND=0 uses VMC(6) everywhere.
// WAR: stage target buf (t+2)%3 last read iter t-1, barrier-separated.
// ---------------------------------------------------------------------------
#define BARR() do { asm volatile("" ::: "memory"); __builtin_amdgcn_s_barrier(); asm volatile("" ::: "memory"); } while (0)
#define VMC_IMPL(N) asm volatile("s_waitcnt vmcnt(" #N ")" ::: "memory")
#define VMC(N) VMC_IMPL(N)

template<int ACT, typename OutT, int BLEND>
__global__ __launch_bounds__(512, 2) void gemm_fused(
    const unsigned short* __restrict__ A,   // M x K bf16 bits
    const unsigned short* __restrict__ Bw,  // N x K bf16 bits
    const float* __restrict__ bias,         // N
    OutT* __restrict__ C,                   // M x N
    const float* __restrict__ Wnext,        // 8 x 2048 x 2048 f32 (or null)
    const float* __restrict__ cb,           // (8,) blend coeffs (or null)
    unsigned short* __restrict__ wbNext)    // 2048 x 2048 bf16 out (or null)
{
    __shared__ __align__(16) unsigned short lds[73728];   // 144 KB
    char* ldsc = (char*)lds;

    const int tid = threadIdx.x;
    const int wid = tid >> 6;
    const int lane = tid & 63;
    const int wr = wid >> 1;      // 0..3 (M)
    const int wc = wid & 1;       // 0..1 (N)

    // blend coeffs: load + fence BEFORE any counted vmem ops.
    float cw[8];
    if (BLEND) {
#pragma unroll
        for (int e = 0; e < 8; ++e) cw[e] = cb[e];
        VMC(0);
    }

    // bijective XCD-chunked swizzle: XCD k gets wg in [k*32,(k+1)*32)
    // = 2 N-panels x 16 M-tiles -> B panels (1MB) L2-resident per XCD.
    const int wg = (blockIdx.x & 7) * 32 + (blockIdx.x >> 3);
    const size_t blockM = (size_t)(wg & 15) * 256;
    const size_t blockN = (size_t)(wg >> 4) * 128;

    // ds_read addressing: swizzled 16B slot within a 128B row.
    const int sw = (lane & 7) << 4;          // (row&7)<<4; row&7 == lane&7
    const int ck = (lane >> 4) << 4;         // k-slot byte base
    const int rAb = wr * 64 + (lane & 15);   // + m*16
    const int rBb = wc * 64 + (lane & 15);   // + n*16

    // staging: thread t writes LDS bytes [tid*16, tid*16+16) of an 8KB
    // 64-row stage; source column pre-XORed (both-sides swizzle).
    const int srow = tid >> 3;                       // 0..63
    const int scol = ((tid & 7) ^ (srow & 7)) << 3;  // element offset
    const unsigned short* aStage = A + (blockM + srow) * KDIM + scol;
    const unsigned short* bStage = Bw + (blockN + srow) * KDIM + scol;

#define STAGE_AS(BUF, S, KT) do { \
    const unsigned short* g_ = aStage + (size_t)(S) * 64 * KDIM + (size_t)(KT) * 64; \
    __builtin_amdgcn_global_load_lds((const __attribute__((address_space(1))) void*)g_, \
        (__attribute__((address_space(3))) void*)(ldsc + (BUF) * 49152 + (S) * 8192 + tid * 16), \
        16, 0, 0); \
} while (0)

#define STAGE_BS(BUF, S, KT) do { \
    const unsigned short* g_ = bStage + (size_t)(S) * 64 * KDIM + (size_t)(KT) * 64; \
    __builtin_amdgcn_global_load_lds((const __attribute__((address_space(1))) void*)g_, \
        (__attribute__((address_space(3))) void*)(ldsc + (BUF) * 49152 + 32768 + (S) * 8192 + tid * 16), \
        16, 0, 0); \
} while (0)

#define RD_A(BUF, M, KK) \
    (*(const bf16x8*)(ldsc + (BUF) * 49152 + ((rAb + (M) * 16)) * 128 + (((KK) * 64 + ck) ^ sw)))
#define RD_B(BUF, N, KK) \
    (*(const bf16x8*)(ldsc + (BUF) * 49152 + 32768 + (rBb + (N) * 16) * 128 + (((KK) * 64 + ck) ^ sw)))

    f32x4 acc[4][4];
#pragma unroll
    for (int m = 0; m < 4; ++m)
#pragma unroll
        for (int n = 0; n < 4; ++n) acc[m][n] = (f32x4){0.f, 0.f, 0.f, 0.f};

    // One GEMM K-iteration: reads tile in buf `cur`, stages tile t+2 into
    // buf (cur+2)%3, MFMAs, then WAITER, barrier, advances cur.
#define GEMM_ITER(T, WAITER) do { \
    int stb_ = cur + 2; if (stb_ >= 3) stb_ -= 3; \
    bf16x8 af[4][2], bfr[4][2]; \
    _Pragma("unroll") for (int m_ = 0; m_ < 4; ++m_) { \
        af[m_][0] = RD_A(cur, m_, 0); af[m_][1] = RD_A(cur, m_, 1); } \
    _Pragma("unroll") for (int n_ = 0; n_ < 4; ++n_) { \
        bfr[n_][0] = RD_B(cur, n_, 0); bfr[n_][1] = RD_B(cur, n_, 1); } \
    if ((T) + 2 < KTILES) { \
        STAGE_AS(stb_, 0, (T) + 2); STAGE_AS(stb_, 1, (T) + 2); \
        STAGE_AS(stb_, 2, (T) + 2); STAGE_AS(stb_, 3, (T) + 2); \
        STAGE_BS(stb_, 0, (T) + 2); STAGE_BS(stb_, 1, (T) + 2); \
    } \
    _Pragma("unroll") for (int kk_ = 0; kk_ < 2; ++kk_) \
    _Pragma("unroll") for (int m_ = 0; m_ < 4; ++m_) \
    _Pragma("unroll") for (int n_ = 0; n_ < 4; ++n_) \
        acc[m_][n_] = __builtin_amdgcn_mfma_f32_16x16x32_bf16( \
            af[m_][kk_], bfr[n_][kk_], acc[m_][n_], 0, 0, 0); \
    WAITER; \
    BARR(); \
    cur = cur + 1; if (cur >= 3) cur = 0; \
} while (0)

    // one blend chunk: this thread blends float4 #(G*131072 + bid*512 + tid)
#define BLEND_STEP(G) do { \
    const unsigned idx_ = (unsigned)(G) * 131072u + (unsigned)blockIdx.x * 512u + (unsigned)tid; \
    const unsigned off_ = idx_ << 2; \
    const float* bs_ = Wnext + off_; \
    float4 s_ = make_float4(0.f, 0.f, 0.f, 0.f); \
    _Pragma("unroll") for (int e_ = 0; e_ < 8; ++e_) { \
        float4 v_ = *(const float4*)(bs_ + (size_t)e_ * PER_LAYER); \
        s_.x += cw[e_] * v_.x; s_.y += cw[e_] * v_.y; \
        s_.z += cw[e_] * v_.z; s_.w += cw[e_] * v_.w; } \
    ushort4 o_; \
    o_.x = f2bf(s_.x); o_.y = f2bf(s_.y); o_.z = f2bf(s_.z); o_.w = f2bf(s_.w); \
    *(ushort4*)(wbNext + off_) = o_; \
} while (0)

    // ---- prologue: tile0 -> buf0, tile1 -> buf1 ----
    STAGE_AS(0, 0, 0); STAGE_AS(0, 1, 0); STAGE_AS(0, 2, 0); STAGE_AS(0, 3, 0);
    STAGE_BS(0, 0, 0); STAGE_BS(0, 1, 0);
    STAGE_AS(1, 0, 1); STAGE_AS(1, 1, 1); STAGE_AS(1, 2, 1); STAGE_AS(1, 3, 1);
    STAGE_BS(1, 0, 1); STAGE_BS(1, 1, 1);
    VMC(6);                       // tile0 landed; tile1's 6 in flight
    BARR();

    int cur = 0;
    if (BLEND) {
#pragma unroll 1
        for (int g = 0; g < 8; ++g) {
            GEMM_ITER(3 * g, VMC(6));
            BLEND_STEP(g);                     // 9 vmem ops at start of iter 3g+1
            GEMM_ITER(3 * g + 1, VMC(15));     // drain S(3g+2); keep blend+S(3g+3)
            GEMM_ITER(3 * g + 2, VMC(6));      // drains blend + S(3g+3)
        }
#pragma unroll 1
        for (int t = 24; t < 30; ++t) GEMM_ITER(t, VMC(6));
    } else {
#pragma unroll 1
        for (int t = 0; t < 30; ++t) GEMM_ITER(t, VMC(6));
    }
    GEMM_ITER(30, VMC(0));        // stages nothing; drains S(31)
    GEMM_ITER(31, VMC(0));        // final tile

    // ---- epilogue: C/D layout col=lane&15 (N), row=(lane>>4)*4+reg (M) ----
    const int crow = (lane >> 4) * 4;
    const int ccol = lane & 15;
#pragma unroll
    for (int m = 0; m < 4; ++m)
#pragma unroll
        for (int n = 0; n < 4; ++n) {
            const size_t col = blockN + wc * 64 + n * 16 + ccol;
            const float bv = bias[col];
#pragma unroll
            for (int r = 0; r < 4; ++r) {
                const size_t row = blockM + wr * 64 + m * 16 + crow + r;
                float v = acc[m][n][r] + bv;
                if (ACT) v = v > 0.f ? v : fast_elu_neg(v);
                if constexpr (sizeof(OutT) == 2) {
                    C[row * NDIM + col] = (OutT)f2bf(v);
                } else {
                    C[row * NDIM + col] = (OutT)v;
                }
            }
        }
#undef STAGE_AS
#undef STAGE_BS
#undef RD_A
#undef RD_B
#undef GEMM_ITER
#undef BLEND_STEP
}

// ---------------------------------------------------------------------------
// Launch: blend0+convert, then 3 chained GEMMs; GEMM0 blends W1, GEMM1
// blends W2 (overlapped with compute), GEMM2 plain.
// Workspace (ushort units): wb[3*PER_LAYER] weights, xb[8388608], y0[8388608].
// ---------------------------------------------------------------------------
extern "C" void kernel_launch(void* const* d_in, const int* in_sizes, int n_in,
                              void* d_out, int out_size, void* d_ws, size_t ws_size,
                              hipStream_t stream) {
    const float* blendw = (const float*)d_in[0];   // (8,)
    const float* x      = (const float*)d_in[1];   // (4096, 2048)
    const float* W      = (const float*)d_in[2];   // (3, 8, 2048, 2048)
    const float* Bb     = (const float*)d_in[3];   // (3, 2048)
    float* out = (float*)d_out;                    // (4096, 2048) f32

    unsigned short* wb0 = (unsigned short*)d_ws;
    unsigned short* wb1 = wb0 + PER_LAYER;
    unsigned short* wb2 = wb1 + PER_LAYER;
    unsigned short* xb  = wb2 + PER_LAYER;
    unsigned short* y0  = xb + 8388608;
    unsigned short* y1  = xb;   // reuse: xb dead after GEMM0

    blend0_kernel<<<2048, 256, 0, stream>>>(W, blendw, x, wb0, xb);

    const int grid = (MDIM / 256) * (NDIM / 128);    // 256 blocks = all CUs
    gemm_fused<1, unsigned short, 1><<<grid, 512, 0, stream>>>(
        xb, wb0, Bb,        y0,  W + (size_t)8 * PER_LAYER,  blendw, wb1);
    gemm_fused<1, unsigned short, 1><<<grid, 512, 0, stream>>>(
        y0, wb1, Bb + 2048, y1,  W + (size_t)16 * PER_LAYER, blendw, wb2);
    gemm_fused<0, float, 0><<<grid, 512, 0, stream>>>(
        y1, wb2, Bb + 4096, out, nullptr, nullptr, nullptr);
}